// Round 1
// baseline (683.105 us; speedup 1.0000x reference)
//
#include <hip/hip_runtime.h>

#define B_SZ 4096
#define D_SZ 128
#define K_SZ 256

constexpr float INV_T    = 1.0f / 0.07f;
constexpr float NOISE    = 255.0f / 1000000.0f;   // (K-1)/N
constexpr float EPS_C    = 1e-7f;
constexpr float K_OVER_N = 256.0f / 1000000.0f;   // K/N

// One block per batch row b; 256 threads; thread t owns sample k = t.
// Each thread streams its own gathered memory row (512 B) with 32
// independent float4 loads. x[b,:] is staged once in LDS (512 B) and
// read back at wave-uniform addresses (hardware broadcast, zero bank
// conflicts). No cross-lane ops in the hot loop -> 64 independent row
// streams per wave, deep memory-level parallelism (vs the previous
// bpermute+5xswizzle chain per 2 rows that capped VMEM depth).
__global__ __launch_bounds__(256, 8) void nce_main(
    const float* __restrict__ x,        // [B, D]
    const int*   __restrict__ targets,  // [B]
    const float* __restrict__ memory,   // [N, D]
    const int*   __restrict__ indices,  // [B, K]
    float*       __restrict__ partial)  // [B]
{
    __shared__ float4 s_x[D_SZ / 4];    // x row: 32 float4 = 512 B
    __shared__ float  s_red[4];

    const int b    = blockIdx.x;
    const int tid  = threadIdx.x;
    const int lane = tid & 63;
    const int wave = tid >> 6;

    if (tid < D_SZ / 4)
        s_x[tid] = ((const float4*)(x + (size_t)b * D_SZ))[tid];

    // col 0 is overwritten with the positive target; coalesced int loads
    const int myidx = (tid == 0) ? targets[b]
                                 : indices[(size_t)b * K_SZ + tid];
    __syncthreads();

    const float4* __restrict__ wrow =
        (const float4*)(memory + (size_t)myidx * D_SZ);

    // 4 interleaved accumulators break the serial FMA dependence chain.
    float a0 = 0.f, a1 = 0.f, a2 = 0.f, a3 = 0.f;
    #pragma unroll
    for (int j = 0; j < D_SZ / 4; j += 4) {
        const float4 w0 = wrow[j + 0];
        const float4 w1 = wrow[j + 1];
        const float4 w2 = wrow[j + 2];
        const float4 w3 = wrow[j + 3];
        const float4 x0 = s_x[j + 0];
        const float4 x1 = s_x[j + 1];
        const float4 x2 = s_x[j + 2];
        const float4 x3 = s_x[j + 3];
        a0 = fmaf(w0.x, x0.x, fmaf(w0.y, x0.y, fmaf(w0.z, x0.z, fmaf(w0.w, x0.w, a0))));
        a1 = fmaf(w1.x, x1.x, fmaf(w1.y, x1.y, fmaf(w1.z, x1.z, fmaf(w1.w, x1.w, a1))));
        a2 = fmaf(w2.x, x2.x, fmaf(w2.y, x2.y, fmaf(w2.z, x2.z, fmaf(w2.w, x2.w, a2))));
        a3 = fmaf(w3.x, x3.x, fmaf(w3.y, x3.y, fmaf(w3.z, x3.z, fmaf(w3.w, x3.w, a3))));
    }
    const float p = (a0 + a1) + (a2 + a3);
    const float e = expf(p * INV_T);

    // block reduce: S = sum_k exp(logit_k)
    float sum = e;
    #pragma unroll
    for (int m = 32; m >= 1; m >>= 1)
        sum += __shfl_xor(sum, m, 64);
    if (lane == 0) s_red[wave] = sum;
    __syncthreads();
    const float S = s_red[0] + s_red[1] + s_red[2] + s_red[3];

    // sims_k = e_k / S * (K/N)
    const float sims = e * (K_OVER_N / S);
    float term = (tid == 0)
        ? logf(sims / (sims + NOISE + EPS_C))    // lnPmt (positive)
        : logf(NOISE / (sims + NOISE + EPS_C));  // lnPon (noise)

    #pragma unroll
    for (int m = 32; m >= 1; m >>= 1)
        term += __shfl_xor(term, m, 64);
    __syncthreads();   // all reads of s_red done before re-use
    if (lane == 0) s_red[wave] = term;
    __syncthreads();
    if (tid == 0)
        partial[b] = s_red[0] + s_red[1] + s_red[2] + s_red[3];
}

// Single-block reduction of the 4096 per-row partials.
__global__ __launch_bounds__(256) void nce_final(
    const float* __restrict__ partial, float* __restrict__ out)
{
    const int tid = threadIdx.x;
    float s = 0.0f;
    #pragma unroll
    for (int i = tid; i < B_SZ; i += 256)
        s += partial[i];
    #pragma unroll
    for (int m = 32; m >= 1; m >>= 1)
        s += __shfl_xor(s, m, 64);
    __shared__ float sr[4];
    if ((tid & 63) == 0) sr[tid >> 6] = s;
    __syncthreads();
    if (tid == 0)
        out[0] = -(sr[0] + sr[1] + sr[2] + sr[3]) / (float)B_SZ;
}

extern "C" void kernel_launch(void* const* d_in, const int* in_sizes, int n_in,
                              void* d_out, int out_size, void* d_ws, size_t ws_size,
                              hipStream_t stream) {
    const float* x       = (const float*)d_in[0];
    const int*   targets = (const int*)  d_in[1];
    const float* memory  = (const float*)d_in[2];
    const int*   indices = (const int*)  d_in[3];
    float* out     = (float*)d_out;
    float* partial = (float*)d_ws;   // B floats of scratch

    nce_main<<<B_SZ, 256, 0, stream>>>(x, targets, memory, indices, partial);
    nce_final<<<1, 256, 0, stream>>>(partial, out);
}